// Round 1
// 907.230 us; speedup vs baseline: 1.0599x; 1.0599x over previous
//
#include <hip/hip_runtime.h>
#include <stdint.h>

#define NE 8
#define NI 2816
#define NH 1024
#define NT 8192
#define NPAIR (NT * 2)

typedef __bf16 bf16x8 __attribute__((ext_vector_type(8)));
typedef float f32x4 __attribute__((ext_vector_type(4)));

__device__ __forceinline__ uint16_t f2bf(float f) {
    union { float f; uint32_t u; } v;
    v.f = f;
    return (uint16_t)((v.u + 0x7FFFu + ((v.u >> 16) & 1u)) >> 16);
}

__device__ __forceinline__ float bflo(uint32_t u) {
    union { uint32_t x; float f; } v; v.x = u << 16; return v.f;
}
__device__ __forceinline__ float bfhi(uint32_t u) {
    union { uint32_t x; float f; } v; v.x = u & 0xffff0000u; return v.f;
}

// async global->LDS, 16B per lane. LDS dest must be lane-contiguous (wave-uniform
// base + lane*16). Generic->AS3 via 32-bit truncation (LDS aperture is 4GB-aligned).
__device__ __forceinline__ void gld16(const void* g, void* l) {
    __builtin_amdgcn_global_load_lds(
        (__attribute__((address_space(1))) void*)(uintptr_t)g,
        (__attribute__((address_space(3))) void*)(uint32_t)(uintptr_t)l,
        16, 0, 0);
}

// ---------------- weight conversion ----------------
// W1/W3 -> Wg interleaved: per expert, Wg row (r>>4)*32 + (W3?16:0) + (r&15)
// so a 256-wide N'-tile pairs 16 W1 cols with the same 16 W3 cols per n-frag pair.
__global__ __launch_bounds__(256) void k_cvt_w13(const float* __restrict__ W1,
                                                 const float* __restrict__ W3,
                                                 uint16_t* __restrict__ Wg) {
    int row = blockIdx.x * 2 + (threadIdx.x >> 7);   // 0 .. NE*NI-1
    int g = threadIdx.x & 127;                       // 8 floats per thread
    const float* src = (blockIdx.y == 0) ? W1 : W3;
    int e = row / NI;
    int r = row - e * NI;
    size_t drow = (size_t)e * (2 * NI) + (size_t)((r >> 4) * 32 + (r & 15) + (blockIdx.y ? 16 : 0));
    const float4* sp = (const float4*)(src + (size_t)row * NH);
    float4 a = sp[g * 2];
    float4 b = sp[g * 2 + 1];
    uint4 o;
    o.x = (uint32_t)f2bf(a.x) | ((uint32_t)f2bf(a.y) << 16);
    o.y = (uint32_t)f2bf(a.z) | ((uint32_t)f2bf(a.w) << 16);
    o.z = (uint32_t)f2bf(b.x) | ((uint32_t)f2bf(b.y) << 16);
    o.w = (uint32_t)f2bf(b.z) | ((uint32_t)f2bf(b.w) << 16);
    ((uint4*)(Wg + drow * NH))[g] = o;
}

__global__ __launch_bounds__(256) void k_cvt_flat(const float* __restrict__ S,
                                                  uint16_t* __restrict__ D) {
    size_t i = (size_t)blockIdx.x * 256 + threadIdx.x;
    float4 a = ((const float4*)S)[i * 2];
    float4 b = ((const float4*)S)[i * 2 + 1];
    uint4 o;
    o.x = (uint32_t)f2bf(a.x) | ((uint32_t)f2bf(a.y) << 16);
    o.y = (uint32_t)f2bf(a.z) | ((uint32_t)f2bf(a.w) << 16);
    o.z = (uint32_t)f2bf(b.x) | ((uint32_t)f2bf(b.y) << 16);
    o.w = (uint32_t)f2bf(b.z) | ((uint32_t)f2bf(b.w) << 16);
    ((uint4*)D)[i] = o;
}

// ---------------- router: top-2 of softmax, renormalized ----------------
__global__ __launch_bounds__(256) void k_router(const float* __restrict__ logits,
                                                int* __restrict__ tok_e,
                                                float2* __restrict__ tok_w,
                                                int* __restrict__ counts) {
    int t = blockIdx.x * 256 + threadIdx.x;
    if (t >= NT) return;
    float4 a = ((const float4*)logits)[(size_t)t * 2];
    float4 b = ((const float4*)logits)[(size_t)t * 2 + 1];
    float l[8] = {a.x, a.y, a.z, a.w, b.x, b.y, b.z, b.w};
    int i0 = 0; float l0 = l[0];
#pragma unroll
    for (int e = 1; e < 8; e++) if (l[e] > l0) { l0 = l[e]; i0 = e; }
    int i1 = -1; float l1 = -3.4e38f;
#pragma unroll
    for (int e = 0; e < 8; e++) if (e != i0 && l[e] > l1) { l1 = l[e]; i1 = e; }
    float w0 = 1.f / (1.f + __expf(l1 - l0));
    float w1 = 1.f - w0;
    tok_e[t] = i0 | (i1 << 8);
    tok_w[t] = make_float2(w0, w1);
    atomicAdd(&counts[i0], 1);
    atomicAdd(&counts[i1], 1);
}

__global__ void k_scan(const int* __restrict__ counts, int* __restrict__ offsets,
                       int* __restrict__ cursor) {
    if (threadIdx.x == 0) {
        int o = 0;
        for (int e = 0; e < NE; e++) { offsets[e] = o; cursor[e] = o; o += counts[e]; }
    }
}

// ---------------- gather routed x rows into per-expert bf16 panels ----------------
__global__ __launch_bounds__(128) void k_gather(const float* __restrict__ x,
                                                const int* __restrict__ tok_e,
                                                const float2* __restrict__ tok_w,
                                                int* __restrict__ cursor,
                                                uint16_t* __restrict__ Xg,
                                                int2* __restrict__ tok_slots,
                                                float* __restrict__ slot_w) {
    int t = blockIdx.x;
    __shared__ int ss[2];
    if (threadIdx.x == 0) {
        int ee = tok_e[t];
        float2 w = tok_w[t];
        int s0 = atomicAdd(&cursor[ee & 0xff], 1);
        int s1 = atomicAdd(&cursor[(ee >> 8) & 0xff], 1);
        ss[0] = s0; ss[1] = s1;
        tok_slots[t] = make_int2(s0, s1);
        slot_w[s0] = w.x;
        slot_w[s1] = w.y;
    }
    __syncthreads();
    int s0 = ss[0], s1 = ss[1];
    int i = threadIdx.x;
    const float4* xr = (const float4*)(x + (size_t)t * NH);
    float4 a = xr[i * 2];
    float4 b = xr[i * 2 + 1];
    uint4 o;
    o.x = (uint32_t)f2bf(a.x) | ((uint32_t)f2bf(a.y) << 16);
    o.y = (uint32_t)f2bf(a.z) | ((uint32_t)f2bf(a.w) << 16);
    o.z = (uint32_t)f2bf(b.x) | ((uint32_t)f2bf(b.y) << 16);
    o.w = (uint32_t)f2bf(b.z) | ((uint32_t)f2bf(b.w) << 16);
    ((uint4*)(Xg + (size_t)s0 * NH))[i] = o;
    ((uint4*)(Xg + (size_t)s1 * NH))[i] = o;
}

// ================= 256x256 8-phase grouped GEMM (T2+T3+T4+T5) =================
// MODE 1: Hbuf = silu(X@W1^T)*(X@W3^T) via interleaved Wg, N'=5632, K=1024
// MODE 2: Ybuf = H @ W2^T, N=1024, K=2816
// 512 threads = 8 waves (2M x 4N), per-wave C = 128x64. LDS 128 KiB:
// [buf(2)][A/B(2)][half(2)] x (128 rows x 64 cols bf16, XOR-swizzled 16B slots).

#define BAR()  asm volatile("s_barrier" ::: "memory")
#define WAITLGKM asm volatile("s_waitcnt lgkmcnt(0)" ::: "memory")
#define WAITV4 asm volatile("s_waitcnt vmcnt(4)" ::: "memory")
#define WAITV0 asm volatile("s_waitcnt vmcnt(0)" ::: "memory")
#define SCHB __builtin_amdgcn_sched_barrier(0)
#define PRIO1 __builtin_amdgcn_s_setprio(1)
#define PRIO0 __builtin_amdgcn_s_setprio(0)

// stage one 128x64 half-tile (16 KiB): linear LDS dest, inverse-swizzled global src
#define STAGE(ab, bufsel, h, kt)                                                  \
    do {                                                                          \
        char* d_ = lds + (bufsel) * 65536 + (ab) * 32768 + (h) * 16384 + tid * 16; \
        gld16(((ab) ? srcB : srcA)[h][0] + (kt) * 64, d_);                         \
        gld16(((ab) ? srcB : srcA)[h][1] + (kt) * 64, d_ + 8192);                  \
    } while (0)

// A frags for m-quadrant mh (4 m-frags x 2 k-slices); wave wr reads only half wr
#define READA(bufsel, mh)                                                           \
    do {                                                                            \
        _Pragma("unroll") for (int ii = 0; ii < 4; ii++) {                          \
            const char* p_ = lds + (bufsel) * 65536 + wr * 16384 +                  \
                             (((mh) * 4 + ii) * 16 + l15) * 128;                    \
            af[ii][0] = *(const bf16x8*)(p_ + colk0);                               \
            af[ii][1] = *(const bf16x8*)(p_ + colk1);                               \
        }                                                                           \
    } while (0)

// B frags for n-half nh (2 n-frags x 2 k-slices) into dst
#define READB(bufsel, nh, dst)                                                      \
    do {                                                                            \
        _Pragma("unroll") for (int jj = 0; jj < 2; jj++) {                          \
            int gb_ = wc * 64 + ((nh) * 2 + jj) * 16;                               \
            const char* p_ = lds + (bufsel) * 65536 + 32768 + (gb_ >> 7) * 16384 +  \
                             ((gb_ & 127) + l15) * 128;                             \
            dst[jj][0] = *(const bf16x8*)(p_ + colk0);                              \
            dst[jj][1] = *(const bf16x8*)(p_ + colk1);                              \
        }                                                                           \
    } while (0)

// one C-quadrant: 4 m-frags x 2 n-frags x K=64  (16 MFMA)
#define MMQ(mh, bsrc, jb)                                                           \
    do {                                                                            \
        _Pragma("unroll") for (int ii = 0; ii < 4; ii++)                            \
            _Pragma("unroll") for (int jj = 0; jj < 2; jj++)                        \
                _Pragma("unroll") for (int ks = 0; ks < 2; ks++)                    \
                    acc[(mh) * 4 + ii][(jb) + jj] =                                 \
                        __builtin_amdgcn_mfma_f32_16x16x32_bf16(                    \
                            af[ii][ks], bsrc[jj][ks], acc[(mh) * 4 + ii][(jb) + jj],\
                            0, 0, 0);                                               \
    } while (0)

// 8 phases = 2 K-tiles (t0=set0, t0+1=set1). Staging plan (tile -> region):
//  P1: set1.A(h0+h1) <- t0+1 | P3: set0.B.h0 <- t0+2 | P4: set0.B.h1 <- t0+2
//  P5: set0.A(h0+h1) <- t0+2 | P7: set1.B.h0 <- t0+3 | P8: set1.B.h1 <- t0+3
// vmcnt(4) at P4/P8 keeps 2 half-tiles in flight across each checkpoint.
#define PHASES(i2, LAST)                                                            \
    do {                                                                            \
        int t1_ = (i2) + 1, t2_ = (i2) + 2, t3_ = (i2) + 3;                         \
        /* P1 */                                                                    \
        READA(0, 0); READB(0, 0, b0);                                               \
        STAGE(0, 1, 0, t1_); STAGE(0, 1, 1, t1_);                                   \
        BAR(); WAITLGKM; SCHB; PRIO1; MMQ(0, b0, 0); PRIO0; SCHB; BAR();            \
        /* P2 */                                                                    \
        READB(0, 1, b1);                                                            \
        BAR(); WAITLGKM; SCHB; PRIO1; MMQ(0, b1, 2); PRIO0; SCHB; BAR();            \
        /* P3 */                                                                    \
        READA(0, 1);                                                                \
        if (!(LAST)) STAGE(1, 0, 0, t2_);                                           \
        BAR(); WAITLGKM; SCHB; PRIO1; MMQ(1, b1, 2); PRIO0; SCHB; BAR();            \
        /* P4 */                                                                    \
        if (!(LAST)) STAGE(1, 0, 1, t2_);                                           \
        BAR(); PRIO1; MMQ(1, b0, 0); PRIO0; SCHB;                                   \
        if (LAST) { WAITV0; } else { WAITV4; }                                      \
        BAR();                                                                      \
        /* P5 */                                                                    \
        READA(1, 0); READB(1, 0, b0);                                               \
        if (!(LAST)) { STAGE(0, 0, 0, t2_); STAGE(0, 0, 1, t2_); }                  \
        BAR(); WAITLGKM; SCHB; PRIO1; MMQ(0, b0, 0); PRIO0; SCHB; BAR();            \
        /* P6 */                                                                    \
        READB(1, 1, b1);                                                            \
        BAR(); WAITLGKM; SCHB; PRIO1; MMQ(0, b1, 2); PRIO0; SCHB; BAR();            \
        /* P7 */                                                                    \
        READA(1, 1);                                                                \
        if (!(LAST)) STAGE(1, 1, 0, t3_);                                           \
        BAR(); WAITLGKM; SCHB; PRIO1; MMQ(1, b1, 2); PRIO0; SCHB; BAR();            \
        /* P8 */                                                                    \
        if (!(LAST)) STAGE(1, 1, 1, t3_);                                           \
        BAR(); PRIO1; MMQ(1, b0, 0); PRIO0; SCHB;                                   \
        if (LAST) { WAITV0; } else { WAITV4; }                                      \
        BAR();                                                                      \
    } while (0)

template <int MODE>
__global__ __launch_bounds__(512, 2) void k_moe_gemm(const uint16_t* __restrict__ Abase,
                                                     const uint16_t* __restrict__ Bbase,
                                                     uint16_t* __restrict__ Cbase,
                                                     const int* __restrict__ counts,
                                                     const int* __restrict__ offsets) {
    constexpr int K = (MODE == 1) ? NH : NI;         // 1024 / 2816
    constexpr int NKT = K / 64;                      // 16 / 44 (even)
    constexpr int NITER = NKT / 2;                   // 8 / 22
    constexpr int BROWS = (MODE == 1) ? 2 * NI : NH; // B rows per expert
    constexpr int CLD = (MODE == 1) ? NI : NH;       // C row stride

    int e = blockIdx.z;
    int n_e = counts[e];
    int mtile = blockIdx.y;
    if (mtile * 256 >= n_e) return;
    int ntile = blockIdx.x;
    int off = offsets[e];

    __shared__ __align__(16) char lds[131072];

    int tid = threadIdx.x;
    int l15 = tid & 15;
    int q = (tid >> 4) & 3;
    int x7 = tid & 7;
    int wv = tid >> 6, wr = wv >> 2, wc = wv & 3;
    int colk0 = (q ^ x7) << 4;         // swizzled byte col, k-slice 0
    int colk1 = ((q + 4) ^ x7) << 4;   // k-slice 1

    // staging: unit u=tid covers (row=tid>>3, phys slot=tid&7) of a half-tile;
    // unit u=tid+512 the same at row+64. logical slot = physslot ^ (row&7).
    int sr = tid >> 3;
    int ss = x7 ^ (sr & 7);
    const uint16_t* srcA[2][2];
    const uint16_t* srcB[2][2];
#pragma unroll
    for (int h = 0; h < 2; h++)
#pragma unroll
        for (int j = 0; j < 2; j++) {
            int gr = off + mtile * 256 + h * 128 + j * 64 + sr;
            gr = min(gr, NPAIR - 1);  // tail rows: read valid garbage, masked at store
            srcA[h][j] = Abase + (size_t)gr * K + ss * 8;
            int gn = ntile * 256 + h * 128 + j * 64 + sr;
            srcB[h][j] = Bbase + (size_t)e * BROWS * K + (size_t)gn * K + ss * 8;
        }

    bf16x8 af[4][2], b0[2][2], b1[2][2];
    f32x4 acc[8][4] = {};

    // prologue: set0 <- tile0 (all 4 halves), set1.B <- tile1
    STAGE(0, 0, 0, 0); STAGE(0, 0, 1, 0);
    STAGE(1, 0, 0, 0); STAGE(1, 0, 1, 0);
    STAGE(1, 1, 0, 1); STAGE(1, 1, 1, 1);
    WAITV4;  // set0 complete, set1.B may be in flight
    BAR();

#pragma unroll 1
    for (int it2 = 0; it2 < NITER - 1; it2++) { PHASES(2 * it2, 0); }
    PHASES(2 * (NITER - 1), 1);

    // epilogue
    int sBase = off + mtile * 256;
    if constexpr (MODE == 1) {
#pragma unroll
        for (int im = 0; im < 8; im++) {
#pragma unroll
            for (int r = 0; r < 4; r++) {
                int lm = wr * 128 + im * 16 + q * 4 + r;
                if (mtile * 256 + lm < n_e) {
                    uint16_t* orow = Cbase + (size_t)(sBase + lm) * CLD +
                                     ntile * 128 + wc * 32 + l15;
#pragma unroll
                    for (int j = 0; j < 2; j++) {
                        float c1 = acc[im][2 * j][r];      // W1 frag
                        float c3 = acc[im][2 * j + 1][r];  // W3 frag (same cols)
                        float hv = (c1 / (1.f + __expf(-c1))) * c3;
                        orow[j * 16] = f2bf(hv);
                    }
                }
            }
        }
    } else {
#pragma unroll
        for (int im = 0; im < 8; im++) {
#pragma unroll
            for (int r = 0; r < 4; r++) {
                int lm = wr * 128 + im * 16 + q * 4 + r;
                if (mtile * 256 + lm < n_e) {
                    uint16_t* orow = Cbase + (size_t)(sBase + lm) * CLD +
                                     ntile * 256 + wc * 64 + l15;
#pragma unroll
                    for (int jn = 0; jn < 4; jn++) orow[jn * 16] = f2bf(acc[im][jn][r]);
                }
            }
        }
    }
}

// ---------------- combine: out[t] = w0*Y[s0] + w1*Y[s1] (fp32) ----------------
__global__ __launch_bounds__(256) void k_combine(const uint16_t* __restrict__ Y,
                                                 const int2* __restrict__ tok_slots,
                                                 const float* __restrict__ slot_w,
                                                 float* __restrict__ out) {
    int idx = blockIdx.x * 256 + threadIdx.x;
    int t = idx >> 7;
    int g = idx & 127;
    int2 s = tok_slots[t];
    float w0 = slot_w[s.x], w1 = slot_w[s.y];
    uint4 u0 = ((const uint4*)(Y + (size_t)s.x * NH))[g];
    uint4 u1 = ((const uint4*)(Y + (size_t)s.y * NH))[g];
    float4 o0, o1;
    o0.x = w0 * bflo(u0.x) + w1 * bflo(u1.x);
    o0.y = w0 * bfhi(u0.x) + w1 * bfhi(u1.x);
    o0.z = w0 * bflo(u0.y) + w1 * bflo(u1.y);
    o0.w = w0 * bfhi(u0.y) + w1 * bfhi(u1.y);
    o1.x = w0 * bflo(u0.z) + w1 * bflo(u1.z);
    o1.y = w0 * bfhi(u0.z) + w1 * bfhi(u1.z);
    o1.z = w0 * bflo(u0.w) + w1 * bflo(u1.w);
    o1.w = w0 * bfhi(u0.w) + w1 * bfhi(u1.w);
    float4* orow = (float4*)(out + (size_t)t * NH + g * 8);
    orow[0] = o0;
    orow[1] = o1;
}

extern "C" void kernel_launch(void* const* d_in, const int* in_sizes, int n_in,
                              void* d_out, int out_size, void* d_ws, size_t ws_size,
                              hipStream_t stream) {
    const float* x = (const float*)d_in[0];
    const float* logits = (const float*)d_in[1];
    const float* W1 = (const float*)d_in[2];
    const float* W3 = (const float*)d_in[3];
    const float* W2 = (const float*)d_in[4];
    float* out = (float*)d_out;

    char* ws = (char*)d_ws;
    size_t o = 0;
    auto nxt = [&](size_t b) -> void* {
        void* p = ws + o;
        o += (b + 255) & ~(size_t)255;
        return p;
    };
    const size_t WELEMS = (size_t)NE * NI * NH;
    uint16_t* Wg = (uint16_t*)nxt(WELEMS * 2 * 2);   // interleaved W1/W3 (2x size)
    uint16_t* W2b = (uint16_t*)nxt(WELEMS * 2);
    uint16_t* Xg = (uint16_t*)nxt((size_t)NPAIR * NH * 2);  // aliased as Ybuf after gemm1
    uint16_t* Hbuf = (uint16_t*)nxt((size_t)NPAIR * NI * 2);
    float* slot_w = (float*)nxt((size_t)NPAIR * 4);
    int2* tok_slots = (int2*)nxt((size_t)NT * 8);
    int* tok_e = (int*)nxt((size_t)NT * 4);
    float2* tok_w = (float2*)nxt((size_t)NT * 8);
    int* meta = (int*)nxt(128);
    int* counts = meta;
    int* offsets = meta + 8;
    int* cursor = meta + 16;
    uint16_t* Ybuf = Xg;
    (void)ws_size; (void)in_sizes; (void)n_in;

    hipMemsetAsync(meta, 0, 128, stream);

    k_router<<<NT / 256, 256, 0, stream>>>(logits, tok_e, tok_w, counts);
    k_scan<<<1, 64, 0, stream>>>(counts, offsets, cursor);

    k_cvt_w13<<<dim3(NE * NI / 2, 2), 256, 0, stream>>>(W1, W3, Wg);
    k_cvt_flat<<<(unsigned)(WELEMS / 8 / 256), 256, 0, stream>>>(W2, W2b);

    k_gather<<<NT, 128, 0, stream>>>(x, tok_e, tok_w, cursor, Xg, tok_slots, slot_w);

    // gemm1: N' = 2*NI = 5632 -> 22 ntiles; mtile covers up to 8192 rows/expert
    k_moe_gemm<1><<<dim3(2 * NI / 256, NT / 256, NE), 512, 0, stream>>>(
        Xg, Wg, Hbuf, counts, offsets);
    // gemm2: N = NH = 1024 -> 4 ntiles
    k_moe_gemm<2><<<dim3(NH / 256, NT / 256, NE), 512, 0, stream>>>(
        Hbuf, W2b, Ybuf, counts, offsets);

    k_combine<<<NT * NH / 8 / 256, 256, 0, stream>>>(Ybuf, tok_slots, slot_w, out);
}

// Round 3
// 885.859 us; speedup vs baseline: 1.0854x; 1.0241x over previous
//
#include <hip/hip_runtime.h>
#include <stdint.h>

#define NE 8
#define NI 2816
#define NH 1024
#define NT 8192
#define NPAIR (NT * 2)

typedef __bf16 bf16x8 __attribute__((ext_vector_type(8)));
typedef float f32x4 __attribute__((ext_vector_type(4)));

__device__ __forceinline__ uint16_t f2bf(float f) {
    union { float f; uint32_t u; } v;
    v.f = f;
    return (uint16_t)((v.u + 0x7FFFu + ((v.u >> 16) & 1u)) >> 16);
}

__device__ __forceinline__ float bflo(uint32_t u) {
    union { uint32_t x; float f; } v; v.x = u << 16; return v.f;
}
__device__ __forceinline__ float bfhi(uint32_t u) {
    union { uint32_t x; float f; } v; v.x = u & 0xffff0000u; return v.f;
}

// async global->LDS, 16B per lane. LDS dest must be lane-contiguous (wave-uniform
// base + lane*16). Generic->AS3 via 32-bit truncation (LDS aperture is 4GB-aligned).
__device__ __forceinline__ void gld16(const void* g, void* l) {
    __builtin_amdgcn_global_load_lds(
        (__attribute__((address_space(1))) void*)(uintptr_t)g,
        (__attribute__((address_space(3))) void*)(uint32_t)(uintptr_t)l,
        16, 0, 0);
}

// ---------------- weight conversion ----------------
// W1/W3 -> Wg interleaved: per expert, Wg row (r>>4)*32 + (W3?16:0) + (r&15)
// so a 256-wide N'-tile pairs 16 W1 cols with the same 16 W3 cols per n-frag pair.
__global__ __launch_bounds__(256) void k_cvt_w13(const float* __restrict__ W1,
                                                 const float* __restrict__ W3,
                                                 uint16_t* __restrict__ Wg) {
    int row = blockIdx.x * 2 + (threadIdx.x >> 7);   // 0 .. NE*NI-1
    int g = threadIdx.x & 127;                       // 8 floats per thread
    const float* src = (blockIdx.y == 0) ? W1 : W3;
    int e = row / NI;
    int r = row - e * NI;
    size_t drow = (size_t)e * (2 * NI) + (size_t)((r >> 4) * 32 + (r & 15) + (blockIdx.y ? 16 : 0));
    const float4* sp = (const float4*)(src + (size_t)row * NH);
    float4 a = sp[g * 2];
    float4 b = sp[g * 2 + 1];
    uint4 o;
    o.x = (uint32_t)f2bf(a.x) | ((uint32_t)f2bf(a.y) << 16);
    o.y = (uint32_t)f2bf(a.z) | ((uint32_t)f2bf(a.w) << 16);
    o.z = (uint32_t)f2bf(b.x) | ((uint32_t)f2bf(b.y) << 16);
    o.w = (uint32_t)f2bf(b.z) | ((uint32_t)f2bf(b.w) << 16);
    ((uint4*)(Wg + drow * NH))[g] = o;
}

__global__ __launch_bounds__(256) void k_cvt_flat(const float* __restrict__ S,
                                                  uint16_t* __restrict__ D) {
    size_t i = (size_t)blockIdx.x * 256 + threadIdx.x;
    float4 a = ((const float4*)S)[i * 2];
    float4 b = ((const float4*)S)[i * 2 + 1];
    uint4 o;
    o.x = (uint32_t)f2bf(a.x) | ((uint32_t)f2bf(a.y) << 16);
    o.y = (uint32_t)f2bf(a.z) | ((uint32_t)f2bf(a.w) << 16);
    o.z = (uint32_t)f2bf(b.x) | ((uint32_t)f2bf(b.y) << 16);
    o.w = (uint32_t)f2bf(b.z) | ((uint32_t)f2bf(b.w) << 16);
    ((uint4*)D)[i] = o;
}

// ---------------- router: top-2 of softmax, renormalized ----------------
__global__ __launch_bounds__(256) void k_router(const float* __restrict__ logits,
                                                int* __restrict__ tok_e,
                                                float2* __restrict__ tok_w,
                                                int* __restrict__ counts) {
    int t = blockIdx.x * 256 + threadIdx.x;
    if (t >= NT) return;
    float4 a = ((const float4*)logits)[(size_t)t * 2];
    float4 b = ((const float4*)logits)[(size_t)t * 2 + 1];
    float l[8] = {a.x, a.y, a.z, a.w, b.x, b.y, b.z, b.w};
    int i0 = 0; float l0 = l[0];
#pragma unroll
    for (int e = 1; e < 8; e++) if (l[e] > l0) { l0 = l[e]; i0 = e; }
    int i1 = -1; float l1 = -3.4e38f;
#pragma unroll
    for (int e = 0; e < 8; e++) if (e != i0 && l[e] > l1) { l1 = l[e]; i1 = e; }
    float w0 = 1.f / (1.f + __expf(l1 - l0));
    float w1 = 1.f - w0;
    tok_e[t] = i0 | (i1 << 8);
    tok_w[t] = make_float2(w0, w1);
    atomicAdd(&counts[i0], 1);
    atomicAdd(&counts[i1], 1);
}

__global__ void k_scan(const int* __restrict__ counts, int* __restrict__ offsets,
                       int* __restrict__ cursor) {
    if (threadIdx.x == 0) {
        int o = 0;
        for (int e = 0; e < NE; e++) { offsets[e] = o; cursor[e] = o; o += counts[e]; }
    }
}

// ---------------- gather routed x rows into per-expert bf16 panels ----------------
__global__ __launch_bounds__(128) void k_gather(const float* __restrict__ x,
                                                const int* __restrict__ tok_e,
                                                const float2* __restrict__ tok_w,
                                                int* __restrict__ cursor,
                                                uint16_t* __restrict__ Xg,
                                                int2* __restrict__ tok_slots,
                                                float* __restrict__ slot_w) {
    int t = blockIdx.x;
    __shared__ int ss[2];
    if (threadIdx.x == 0) {
        int ee = tok_e[t];
        float2 w = tok_w[t];
        int s0 = atomicAdd(&cursor[ee & 0xff], 1);
        int s1 = atomicAdd(&cursor[(ee >> 8) & 0xff], 1);
        ss[0] = s0; ss[1] = s1;
        tok_slots[t] = make_int2(s0, s1);
        slot_w[s0] = w.x;
        slot_w[s1] = w.y;
    }
    __syncthreads();
    int s0 = ss[0], s1 = ss[1];
    int i = threadIdx.x;
    const float4* xr = (const float4*)(x + (size_t)t * NH);
    float4 a = xr[i * 2];
    float4 b = xr[i * 2 + 1];
    uint4 o;
    o.x = (uint32_t)f2bf(a.x) | ((uint32_t)f2bf(a.y) << 16);
    o.y = (uint32_t)f2bf(a.z) | ((uint32_t)f2bf(a.w) << 16);
    o.z = (uint32_t)f2bf(b.x) | ((uint32_t)f2bf(b.y) << 16);
    o.w = (uint32_t)f2bf(b.z) | ((uint32_t)f2bf(b.w) << 16);
    ((uint4*)(Xg + (size_t)s0 * NH))[i] = o;
    ((uint4*)(Xg + (size_t)s1 * NH))[i] = o;
}

// ================= 256x256 8-phase grouped GEMM, deep-pipelined =================
// MODE 1: Hbuf = silu(X@W1^T)*(X@W3^T) via interleaved Wg, N'=5632, K=1024
// MODE 2: Ybuf = H @ W2^T, N=1024, K=2816
// 512 threads = 8 waves (2M x 4N), per-wave C = 128x64. LDS 128 KiB:
// [set(2)][A/B(2)][half(2)] x (128 rows x 64 cols bf16, XOR-swizzled 16B slots).
//
// Schedule per iteration (tiles T=2i in set0, T+1 in set1), ONE barrier/phase:
//  P1: read s0{A0,B0,B1}(16 ds), stage s1.A.h1<-T+1, lgkm(4), MFMA Q00
//  P2: stage s0.B.h0<-T+2, lgkm(0)[B1], MFMA Q01, read s0.A1 (8 ds, WAR on af)
//  P3: stage s0.B.h1<-T+2, lgkm(0)[A1], MFMA Q11
//  P4: stage s0.A.h0<-T+2, MFMA Q10, vmcnt(6)   [retires ...set1 halves]
//  P5..P8 mirror on set1 (stages: s0.A.h1<-T+2, s1.B.h0/h1<-T+3, s1.A.h0<-T+3)
// vmcnt(6) FIFO proof: at P4, outstanding = prev{P6,P7,P8}+{P1..P4} = 14 ->
// retire 8 = prev{P6,P7,P8}+P1 = exactly set1's 4 halves; in-flight 6 = P2,P3,P4.
// Newest retired load was issued 3 full phases before the wait (no stall).
// Last iteration restages tile NKT-1 (clamped, garbage, never read); the loop
// exits with 6 loads in flight -> MUST drain vmcnt(0) before s_endpgm, else the
// LDS-DMA lands in deallocated LDS (round-2 fault).

#define BAR()  asm volatile("s_barrier" ::: "memory")
#define WAITLGKM0 asm volatile("s_waitcnt lgkmcnt(0)" ::: "memory")
#define WAITLGKM4 asm volatile("s_waitcnt lgkmcnt(4)" ::: "memory")
#define WAITV6 asm volatile("s_waitcnt vmcnt(6)" ::: "memory")
#define WAITV0 asm volatile("s_waitcnt vmcnt(0)" ::: "memory")
#define SCHB __builtin_amdgcn_sched_barrier(0)
#define PRIO1 __builtin_amdgcn_s_setprio(1)
#define PRIO0 __builtin_amdgcn_s_setprio(0)

// stage one 128x64 half-tile (16 KiB): linear LDS dest, inverse-swizzled global src
#define STAGE(ab, bufsel, h, kt)                                                  \
    do {                                                                          \
        char* d_ = lds + (bufsel) * 65536 + (ab) * 32768 + (h) * 16384 + tid * 16; \
        gld16(((ab) ? srcB : srcA)[h][0] + (kt) * 64, d_);                         \
        gld16(((ab) ? srcB : srcA)[h][1] + (kt) * 64, d_ + 8192);                  \
    } while (0)

// A frags for m-quadrant mh (4 m-frags x 2 k-slices); wave wr reads only half wr
#define READA(bufsel, mh)                                                           \
    do {                                                                            \
        _Pragma("unroll") for (int ii = 0; ii < 4; ii++) {                          \
            const char* p_ = lds + (bufsel) * 65536 + wr * 16384 +                  \
                             (((mh) * 4 + ii) * 16 + l15) * 128;                    \
            af[ii][0] = *(const bf16x8*)(p_ + colk0);                               \
            af[ii][1] = *(const bf16x8*)(p_ + colk1);                               \
        }                                                                           \
    } while (0)

// B frags for n-half nh (2 n-frags x 2 k-slices) into dst
#define READB(bufsel, nh, dst)                                                      \
    do {                                                                            \
        _Pragma("unroll") for (int jj = 0; jj < 2; jj++) {                          \
            int gb_ = wc * 64 + ((nh) * 2 + jj) * 16;                               \
            const char* p_ = lds + (bufsel) * 65536 + 32768 + (gb_ >> 7) * 16384 +  \
                             ((gb_ & 127) + l15) * 128;                             \
            dst[jj][0] = *(const bf16x8*)(p_ + colk0);                              \
            dst[jj][1] = *(const bf16x8*)(p_ + colk1);                              \
        }                                                                           \
    } while (0)

// one C-quadrant: 4 m-frags x 2 n-frags x K=64  (16 MFMA)
#define MMQ(mh, bsrc, jb)                                                           \
    do {                                                                            \
        _Pragma("unroll") for (int ii = 0; ii < 4; ii++)                            \
            _Pragma("unroll") for (int jj = 0; jj < 2; jj++)                        \
                _Pragma("unroll") for (int ks = 0; ks < 2; ks++)                    \
                    acc[(mh) * 4 + ii][(jb) + jj] =                                 \
                        __builtin_amdgcn_mfma_f32_16x16x32_bf16(                    \
                            af[ii][ks], bsrc[jj][ks], acc[(mh) * 4 + ii][(jb) + jj],\
                            0, 0, 0);                                               \
    } while (0)

template <int MODE>
__global__ __launch_bounds__(512, 2) void k_moe_gemm(const uint16_t* __restrict__ Abase,
                                                     const uint16_t* __restrict__ Bbase,
                                                     uint16_t* __restrict__ Cbase,
                                                     const int* __restrict__ counts,
                                                     const int* __restrict__ offsets) {
    constexpr int K = (MODE == 1) ? NH : NI;         // 1024 / 2816
    constexpr int NKT = K / 64;                      // 16 / 44 (even)
    constexpr int NITER = NKT / 2;                   // 8 / 22
    constexpr int BROWS = (MODE == 1) ? 2 * NI : NH; // B rows per expert
    constexpr int CLD = (MODE == 1) ? NI : NH;       // C row stride

    int e = blockIdx.z;
    int n_e = counts[e];
    int mtile = blockIdx.y;
    if (mtile * 256 >= n_e) return;
    int ntile = blockIdx.x;
    int off = offsets[e];

    __shared__ __align__(16) char lds[131072];

    int tid = threadIdx.x;
    int l15 = tid & 15;
    int q = (tid >> 4) & 3;
    int x7 = tid & 7;
    int wv = tid >> 6, wr = wv >> 2, wc = wv & 3;
    int colk0 = (q ^ x7) << 4;         // swizzled byte col, k-slice 0
    int colk1 = ((q + 4) ^ x7) << 4;   // k-slice 1

    // staging: unit u=tid covers (row=tid>>3, phys slot=tid&7) of a half-tile;
    // second gld16 covers row+64. logical slot = physslot ^ (row&7).
    int sr = tid >> 3;
    int ss = x7 ^ (sr & 7);
    const uint16_t* srcA[2][2];
    const uint16_t* srcB[2][2];
#pragma unroll
    for (int h = 0; h < 2; h++)
#pragma unroll
        for (int j = 0; j < 2; j++) {
            int gr = off + mtile * 256 + h * 128 + j * 64 + sr;
            gr = min(gr, NPAIR - 1);  // tail rows: read valid garbage, masked at store
            srcA[h][j] = Abase + (size_t)gr * K + ss * 8;
            int gn = ntile * 256 + h * 128 + j * 64 + sr;
            srcB[h][j] = Bbase + (size_t)e * BROWS * K + (size_t)gn * K + ss * 8;
        }

    bf16x8 af[4][2], b0[2][2], b1[2][2];
    f32x4 acc[8][4] = {};

    // prologue = steady-state stage FIFO of a virtual previous iteration:
    // [s0.B.h0, s0.B.h1, s0.A.h0, s0.A.h1] <- tile0, [s1.B.h0, s1.B.h1, s1.A.h0] <- tile1
    STAGE(1, 0, 0, 0);
    STAGE(1, 0, 1, 0);
    STAGE(0, 0, 0, 0);
    STAGE(0, 0, 1, 0);
    STAGE(1, 1, 0, 1);
    STAGE(1, 1, 1, 1);
    STAGE(0, 1, 0, 1);
    WAITV6;  // 14 outstanding -> retire 8 = all of set0; s1 halves stay in flight
    BAR();

#pragma unroll 1
    for (int it = 0; it < NITER; ++it) {
        int kt1 = 2 * it + 1;
        int kt2 = min(2 * it + 2, NKT - 1);
        int kt3 = min(2 * it + 3, NKT - 1);
        // ---- P1 ----
        READA(0, 0);
        READB(0, 0, b0);
        READB(0, 1, b1);                 // B1 early (issued last -> lgkm(4) skips it)
        STAGE(0, 1, 1, kt1);             // s1.A.h1 <- T+1
        WAITLGKM4; SCHB; PRIO1; MMQ(0, b0, 0); PRIO0; SCHB;
        BAR();
        // ---- P2 ----
        STAGE(1, 0, 0, kt2);             // s0.B.h0 <- T+2
        WAITLGKM0; SCHB; PRIO1; MMQ(0, b1, 2); PRIO0; SCHB;
        READA(0, 1);                     // A1 into af (WAR: after Q01's last A0 use)
        BAR();
        // ---- P3 ----
        STAGE(1, 0, 1, kt2);             // s0.B.h1
        WAITLGKM0; SCHB; PRIO1; MMQ(1, b1, 2); PRIO0; SCHB;
        BAR();
        // ---- P4 ----
        STAGE(0, 0, 0, kt2);             // s0.A.h0
        PRIO1; MMQ(1, b0, 0); PRIO0; SCHB;
        WAITV6;                          // retires prev{P6,P7,P8}+P1 = set1 ready
        BAR();
        // ---- P5 ----
        READA(1, 0);
        READB(1, 0, b0);
        READB(1, 1, b1);
        STAGE(0, 0, 1, kt2);             // s0.A.h1
        WAITLGKM4; SCHB; PRIO1; MMQ(0, b0, 0); PRIO0; SCHB;
        BAR();
        // ---- P6 ----
        STAGE(1, 1, 0, kt3);             // s1.B.h0 <- T+3
        WAITLGKM0; SCHB; PRIO1; MMQ(0, b1, 2); PRIO0; SCHB;
        READA(1, 1);
        BAR();
        // ---- P7 ----
        STAGE(1, 1, 1, kt3);             // s1.B.h1
        WAITLGKM0; SCHB; PRIO1; MMQ(1, b1, 2); PRIO0; SCHB;
        BAR();
        // ---- P8 ----
        STAGE(0, 1, 0, kt3);             // s1.A.h0
        PRIO1; MMQ(1, b0, 0); PRIO0; SCHB;
        WAITV6;                          // retires P2..P5 = set0 ready for next P1
        BAR();
    }

    WAITV0;  // drain tail LDS-DMA before epilogue/endpgm (round-2 fault fix)

    // epilogue
    int sBase = off + mtile * 256;
    if constexpr (MODE == 1) {
#pragma unroll
        for (int im = 0; im < 8; im++) {
#pragma unroll
            for (int r = 0; r < 4; r++) {
                int lm = wr * 128 + im * 16 + q * 4 + r;
                if (mtile * 256 + lm < n_e) {
                    uint16_t* orow = Cbase + (size_t)(sBase + lm) * CLD +
                                     ntile * 128 + wc * 32 + l15;
#pragma unroll
                    for (int j = 0; j < 2; j++) {
                        float c1 = acc[im][2 * j][r];      // W1 frag
                        float c3 = acc[im][2 * j + 1][r];  // W3 frag (same cols)
                        float hv = (c1 / (1.f + __expf(-c1))) * c3;
                        orow[j * 16] = f2bf(hv);
                    }
                }
            }
        }
    } else {
#pragma unroll
        for (int im = 0; im < 8; im++) {
#pragma unroll
            for (int r = 0; r < 4; r++) {
                int lm = wr * 128 + im * 16 + q * 4 + r;
                if (mtile * 256 + lm < n_e) {
                    uint16_t* orow = Cbase + (size_t)(sBase + lm) * CLD +
                                     ntile * 256 + wc * 64 + l15;
#pragma unroll
                    for (int jn = 0; jn < 4; jn++) orow[jn * 16] = f2bf(acc[im][jn][r]);
                }
            }
        }
    }
}

// ---------------- combine: out[t] = w0*Y[s0] + w1*Y[s1] (fp32) ----------------
__global__ __launch_bounds__(256) void k_combine(const uint16_t* __restrict__ Y,
                                                 const int2* __restrict__ tok_slots,
                                                 const float* __restrict__ slot_w,
                                                 float* __restrict__ out) {
    int idx = blockIdx.x * 256 + threadIdx.x;
    int t = idx >> 7;
    int g = idx & 127;
    int2 s = tok_slots[t];
    float w0 = slot_w[s.x], w1 = slot_w[s.y];
    uint4 u0 = ((const uint4*)(Y + (size_t)s.x * NH))[g];
    uint4 u1 = ((const uint4*)(Y + (size_t)s.y * NH))[g];
    float4 o0, o1;
    o0.x = w0 * bflo(u0.x) + w1 * bflo(u1.x);
    o0.y = w0 * bfhi(u0.x) + w1 * bfhi(u1.x);
    o0.z = w0 * bflo(u0.y) + w1 * bflo(u1.y);
    o0.w = w0 * bfhi(u0.y) + w1 * bfhi(u1.y);
    o1.x = w0 * bflo(u0.z) + w1 * bflo(u1.z);
    o1.y = w0 * bfhi(u0.z) + w1 * bfhi(u1.z);
    o1.z = w0 * bflo(u0.w) + w1 * bflo(u1.w);
    o1.w = w0 * bfhi(u0.w) + w1 * bfhi(u1.w);
    float4* orow = (float4*)(out + (size_t)t * NH + g * 8);
    orow[0] = o0;
    orow[1] = o1;
}

extern "C" void kernel_launch(void* const* d_in, const int* in_sizes, int n_in,
                              void* d_out, int out_size, void* d_ws, size_t ws_size,
                              hipStream_t stream) {
    const float* x = (const float*)d_in[0];
    const float* logits = (const float*)d_in[1];
    const float* W1 = (const float*)d_in[2];
    const float* W3 = (const float*)d_in[3];
    const float* W2 = (const float*)d_in[4];
    float* out = (float*)d_out;

    char* ws = (char*)d_ws;
    size_t o = 0;
    auto nxt = [&](size_t b) -> void* {
        void* p = ws + o;
        o += (b + 255) & ~(size_t)255;
        return p;
    };
    const size_t WELEMS = (size_t)NE * NI * NH;
    uint16_t* Wg = (uint16_t*)nxt(WELEMS * 2 * 2);   // interleaved W1/W3 (2x size)
    uint16_t* W2b = (uint16_t*)nxt(WELEMS * 2);
    uint16_t* Xg = (uint16_t*)nxt((size_t)NPAIR * NH * 2);  // aliased as Ybuf after gemm1
    uint16_t* Hbuf = (uint16_t*)nxt((size_t)NPAIR * NI * 2);
    float* slot_w = (float*)nxt((size_t)NPAIR * 4);
    int2* tok_slots = (int2*)nxt((size_t)NT * 8);
    int* tok_e = (int*)nxt((size_t)NT * 4);
    float2* tok_w = (float2*)nxt((size_t)NT * 8);
    int* meta = (int*)nxt(128);
    int* counts = meta;
    int* offsets = meta + 8;
    int* cursor = meta + 16;
    uint16_t* Ybuf = Xg;
    (void)ws_size; (void)in_sizes; (void)n_in;

    hipMemsetAsync(meta, 0, 128, stream);

    k_router<<<NT / 256, 256, 0, stream>>>(logits, tok_e, tok_w, counts);
    k_scan<<<1, 64, 0, stream>>>(counts, offsets, cursor);

    k_cvt_w13<<<dim3(NE * NI / 2, 2), 256, 0, stream>>>(W1, W3, Wg);
    k_cvt_flat<<<(unsigned)(WELEMS / 8 / 256), 256, 0, stream>>>(W2, W2b);

    k_gather<<<NT, 128, 0, stream>>>(x, tok_e, tok_w, cursor, Xg, tok_slots, slot_w);

    // gemm1: N' = 2*NI = 5632 -> 22 ntiles
    k_moe_gemm<1><<<dim3(2 * NI / 256, NT / 256, NE), 512, 0, stream>>>(
        Xg, Wg, Hbuf, counts, offsets);
    // gemm2: N = NH = 1024 -> 4 ntiles
    k_moe_gemm<2><<<dim3(NH / 256, NT / 256, NE), 512, 0, stream>>>(
        Hbuf, W2b, Ybuf, counts, offsets);

    k_combine<<<NT * NH / 8 / 256, 256, 0, stream>>>(Ybuf, tok_slots, slot_w, out);
}